// Round 1
// baseline (1701.966 us; speedup 1.0000x reference)
//
#include <hip/hip_runtime.h>
#include <math.h>

#define EPSF 1e-5f

static __device__ __forceinline__ float bcastlane(float v, int l) {
  return __int_as_float(__builtin_amdgcn_readlane(__float_as_int(v), l));
}

// ---------------- init / histogram / scan / scatter (CSR build) -------------

__global__ __launch_bounds__(256) void k_init(int* __restrict__ deg,
                                              float* __restrict__ bn_sum,
                                              float* __restrict__ bn_ssq, int N) {
  int i = blockIdx.x * 256 + threadIdx.x;
  if (i < N) deg[i] = 0;
  if (i < 64) { bn_sum[i] = 0.f; bn_ssq[i] = 0.f; }
}

__global__ __launch_bounds__(256) void k_deg(const int* __restrict__ dst,
                                             int* __restrict__ deg, int E) {
  int i = blockIdx.x * 256 + threadIdx.x;
  if (i < E) atomicAdd(&deg[dst[i]], 1);
}

__global__ __launch_bounds__(1024) void k_scan_a(const int* __restrict__ deg,
                                                 int* __restrict__ offs,
                                                 int* __restrict__ bsum, int N) {
  __shared__ int s[1024];
  int t = threadIdx.x;
  int i = blockIdx.x * 1024 + t;
  int v = (i < N) ? deg[i] : 0;
  s[t] = v;
  __syncthreads();
  for (int off = 1; off < 1024; off <<= 1) {
    int x = (t >= off) ? s[t - off] : 0;
    __syncthreads();
    s[t] += x;
    __syncthreads();
  }
  if (i < N) offs[i] = s[t] - v;  // exclusive within block
  if (t == 1023) bsum[blockIdx.x] = s[1023];
}

__global__ __launch_bounds__(1024) void k_scan_b(int* __restrict__ bsum, int nb) {
  __shared__ int s[1024];
  int t = threadIdx.x;
  int v = (t < nb) ? bsum[t] : 0;
  s[t] = v;
  __syncthreads();
  for (int off = 1; off < 1024; off <<= 1) {
    int x = (t >= off) ? s[t - off] : 0;
    __syncthreads();
    s[t] += x;
    __syncthreads();
  }
  if (t < nb) bsum[t] = s[t] - v;  // exclusive
}

__global__ __launch_bounds__(1024) void k_scan_c(int* __restrict__ offs,
                                                 const int* __restrict__ bsum,
                                                 int* __restrict__ cursor, int N) {
  int i = blockIdx.x * 1024 + threadIdx.x;
  if (i < N) {
    int o = offs[i] + bsum[blockIdx.x];
    offs[i] = o;
    cursor[i] = o;
  }
}

__global__ __launch_bounds__(256) void k_scatter(const int* __restrict__ dst,
                                                 int* __restrict__ cursor,
                                                 int* __restrict__ csr, int E) {
  int i = blockIdx.x * 256 + threadIdx.x;
  if (i < E) {
    int d = dst[i];
    int pos = atomicAdd(&cursor[d], 1);
    csr[pos] = i;
  }
}

// ------------- phase 1: fused edge MLP + multi-aggregator reduce ------------
// 1 wave per node, 4 waves (256 thr) per block. pre_W staged in LDS once,
// then hoisted into 80 VGPRs per lane (the rows touched per edge).

__global__ __launch_bounds__(256) void k_edge_agg(
    const float* __restrict__ node_feat, const float* __restrict__ edge_feat,
    const float* __restrict__ pre_W, const float* __restrict__ pre_b,
    const int* __restrict__ src, const int* __restrict__ offs,
    const int* __restrict__ deg, const int* __restrict__ csr,
    float* __restrict__ agg, float* __restrict__ aux, int N) {
  __shared__ float Wl[144 * 64];
  int tid = threadIdx.x;
  for (int idx = tid; idx < 144 * 64; idx += 256) Wl[idx] = pre_W[idx];
  __syncthreads();

  int lane = tid & 63;
  int n = blockIdx.x * 4 + (tid >> 6);
  if (n >= N) return;

  // hoist per-edge W rows into registers: rows 0..63 (h_src), 128..143 (e_feat)
  float wreg[80];
#pragma unroll
  for (int k = 0; k < 64; k++) wreg[k] = Wl[k * 64 + lane];
#pragma unroll
  for (int k = 0; k < 16; k++) wreg[64 + k] = Wl[(128 + k) * 64 + lane];

  int beg = offs[n];
  int dc = deg[n];

  // per-node constant part: pre_b + h_dst @ W[64:128]
  float hd = node_feat[(long)n * 64 + lane];
  float base = pre_b[lane];
#pragma unroll
  for (int k = 0; k < 64; k++)
    base = fmaf(bcastlane(hd, k), Wl[(64 + k) * 64 + lane], base);

  float sum = 0.f, ssq = 0.f, mx = -3.4e38f, mn = 3.4e38f;
  for (int ii = 0; ii < dc; ii++) {
    int eid = csr[beg + ii];
    int sn = src[eid];
    float hs = node_feat[(long)sn * 64 + lane];
    float ef = (lane < 16) ? edge_feat[(long)eid * 16 + lane] : 0.f;
    float acca = base, accb = 0.f;
#pragma unroll
    for (int k = 0; k < 64; k += 2) {
      acca = fmaf(bcastlane(hs, k), wreg[k], acca);
      accb = fmaf(bcastlane(hs, k + 1), wreg[k + 1], accb);
    }
#pragma unroll
    for (int k = 0; k < 16; k += 2) {
      acca = fmaf(bcastlane(ef, k), wreg[64 + k], acca);
      accb = fmaf(bcastlane(ef, k + 1), wreg[65 + k], accb);
    }
    float ev = fmaxf(acca + accb, 0.f);
    sum += ev;
    ssq = fmaf(ev, ev, ssq);
    mx = fmaxf(mx, ev);
    mn = fminf(mn, ev);
  }

  float mean, stdv, mxo, mno, logD, attf;
  if (dc > 0) {
    float degf = (float)dc;
    mean = sum / degf;
    float msq = ssq / degf;
    float var = fmaxf(msq - mean * mean, 0.f);
    stdv = sqrtf(var + EPSF);
    mxo = mx;
    mno = mn;
    logD = logf(degf + 1.f);
    attf = 1.f / fmaxf(logD, EPSF);
  } else {
    mean = 0.f; stdv = 0.f; mxo = 0.f; mno = 0.f; logD = 0.f; attf = 0.f;
  }
  long b = (long)n * 256;
  agg[b + lane] = mean;
  agg[b + 64 + lane] = mxo;
  agg[b + 128 + lane] = mno;
  agg[b + 192 + lane] = stdv;
  if (lane == 0) {
    aux[n * 2] = logD;
    aux[n * 2 + 1] = attf;
  }
}

// ------------- phase 2: x1 = relu([h|agg|amp|att] @ W1 + b1), BN partials ---
// 16 nodes/block, 4 waves, each wave 4 nodes; W1 streamed through LDS chunks.

__global__ __launch_bounds__(256) void k_post1(
    const float* __restrict__ node_feat, const float* __restrict__ agg,
    const float* __restrict__ aux, const float* __restrict__ post_W1,
    const float* __restrict__ post_b1, float* __restrict__ x1,
    float* __restrict__ bn_sum, float* __restrict__ bn_ssq, int N) {
  __shared__ float ht[16 * 832];   // 52 KB
  __shared__ float wch[32 * 64];   // 8 KB
  __shared__ float red[8 * 64];    // 2 KB
  int tid = threadIdx.x;
  int n0 = blockIdx.x * 16;

  for (int idx = tid; idx < 16 * 832; idx += 256) {
    int m = idx / 832;
    int c = idx - m * 832;
    int n = n0 + m;
    float v = 0.f;
    if (n < N) {
      if (c < 64) {
        v = node_feat[(long)n * 64 + c];
      } else {
        int q = c - 64;
        int grp = q >> 8;   // 0: agg, 1: amp, 2: att
        int qq = q & 255;
        float a = agg[(long)n * 256 + qq];
        if (grp == 0) v = a;
        else if (grp == 1) v = a * aux[n * 2];
        else v = a * aux[n * 2 + 1];
      }
    }
    ht[idx] = v;
  }

  int lane = tid & 63, w = tid >> 6;
  int nb = w * 4;
  const int hb0 = nb * 832, hb1 = (nb + 1) * 832, hb2 = (nb + 2) * 832,
            hb3 = (nb + 3) * 832;
  float acc0 = 0.f, acc1 = 0.f, acc2 = 0.f, acc3 = 0.f;

  for (int kc = 0; kc < 26; kc++) {
    __syncthreads();
    for (int idx = tid; idx < 32 * 64; idx += 256)
      wch[idx] = post_W1[kc * 2048 + idx];
    __syncthreads();
#pragma unroll
    for (int k = 0; k < 32; k++) {
      float wv = wch[k * 64 + lane];
      int kk = kc * 32 + k;
      acc0 = fmaf(ht[hb0 + kk], wv, acc0);
      acc1 = fmaf(ht[hb1 + kk], wv, acc1);
      acc2 = fmaf(ht[hb2 + kk], wv, acc2);
      acc3 = fmaf(ht[hb3 + kk], wv, acc3);
    }
  }

  float b1v = post_b1[lane];
  float s = 0.f, s2 = 0.f;
  {
    int n = n0 + nb;
    float x;
    if (n < N) { x = fmaxf(acc0 + b1v, 0.f); x1[(long)n * 64 + lane] = x; s += x; s2 = fmaf(x, x, s2); }
    if (n + 1 < N) { x = fmaxf(acc1 + b1v, 0.f); x1[(long)(n + 1) * 64 + lane] = x; s += x; s2 = fmaf(x, x, s2); }
    if (n + 2 < N) { x = fmaxf(acc2 + b1v, 0.f); x1[(long)(n + 2) * 64 + lane] = x; s += x; s2 = fmaf(x, x, s2); }
    if (n + 3 < N) { x = fmaxf(acc3 + b1v, 0.f); x1[(long)(n + 3) * 64 + lane] = x; s += x; s2 = fmaf(x, x, s2); }
  }
  red[w * 64 + lane] = s;
  red[(4 + w) * 64 + lane] = s2;
  __syncthreads();
  if (w == 0) {
    float st = red[lane] + red[64 + lane] + red[128 + lane] + red[192 + lane];
    float st2 = red[256 + lane] + red[320 + lane] + red[384 + lane] + red[448 + lane];
    atomicAdd(&bn_sum[lane], st);
    atomicAdd(&bn_ssq[lane], st2);
  }
}

// ------------- phase 3: BN stats finalize -----------------------------------

__global__ __launch_bounds__(64) void k_bnstat(
    const float* __restrict__ bn_sum, const float* __restrict__ bn_ssq,
    const float* __restrict__ gamma, const float* __restrict__ beta,
    float* __restrict__ scale, float* __restrict__ shift, float invN) {
  int j = threadIdx.x;
  float mu = bn_sum[j] * invN;
  float v = fmaxf(bn_ssq[j] * invN - mu * mu, 0.f);
  float sc = gamma[j] / sqrtf(v + EPSF);
  scale[j] = sc;
  shift[j] = beta[j] - mu * sc;
}

// ------------- phase 4: out = relu(BN(x1) @ W2 + b2) + h_in -----------------

__global__ __launch_bounds__(256) void k_post2(
    const float* __restrict__ x1, const float* __restrict__ post_W2,
    const float* __restrict__ post_b2, const float* __restrict__ scale,
    const float* __restrict__ shift, const float* __restrict__ node_feat,
    float* __restrict__ out, int N) {
  __shared__ float W2l[64 * 64];
  int tid = threadIdx.x;
  for (int idx = tid; idx < 4096; idx += 256) W2l[idx] = post_W2[idx];
  __syncthreads();
  int lane = tid & 63;
  int n = blockIdx.x * 4 + (tid >> 6);
  if (n >= N) return;
  float xv = x1[(long)n * 64 + lane] * scale[lane] + shift[lane];
  float acca = post_b2[lane], accb = 0.f;
#pragma unroll
  for (int k = 0; k < 64; k += 2) {
    acca = fmaf(bcastlane(xv, k), W2l[k * 64 + lane], acca);
    accb = fmaf(bcastlane(xv, k + 1), W2l[(k + 1) * 64 + lane], accb);
  }
  out[(long)n * 64 + lane] = fmaxf(acca + accb, 0.f) + node_feat[(long)n * 64 + lane];
}

// ----------------------------------------------------------------------------

extern "C" void kernel_launch(void* const* d_in, const int* in_sizes, int n_in,
                              void* d_out, int out_size, void* d_ws, size_t ws_size,
                              hipStream_t stream) {
  const float* node_feat = (const float*)d_in[0];
  const float* edge_feat = (const float*)d_in[1];
  const float* pre_W = (const float*)d_in[2];
  const float* pre_b = (const float*)d_in[3];
  const float* post_W1 = (const float*)d_in[4];
  const float* post_b1 = (const float*)d_in[5];
  const float* bn_gamma = (const float*)d_in[6];
  const float* bn_beta = (const float*)d_in[7];
  const float* post_W2 = (const float*)d_in[8];
  const float* post_b2 = (const float*)d_in[9];
  const int* src = (const int*)d_in[10];
  const int* dst = (const int*)d_in[11];
  float* out = (float*)d_out;

  int N = in_sizes[0] / 64;
  int E = in_sizes[10];

  // workspace carve-up (256B aligned)
  char* ws = (char*)d_ws;
  size_t off = 0;
  auto alloc = [&](size_t bytes) -> void* {
    void* p = ws + off;
    off += (bytes + 255) & ~(size_t)255;
    return p;
  };
  int* deg = (int*)alloc((size_t)N * 4);
  int* offs = (int*)alloc((size_t)N * 4);
  int* cursor = (int*)alloc((size_t)N * 4);
  int* csr = (int*)alloc((size_t)E * 4);
  int* bsum = (int*)alloc(1024 * 4);
  float* agg = (float*)alloc((size_t)N * 256 * 4);
  float* aux = (float*)alloc((size_t)N * 2 * 4);
  float* x1 = (float*)alloc((size_t)N * 64 * 4);
  float* bn_sum = (float*)alloc(64 * 4);
  float* bn_ssq = (float*)alloc(64 * 4);
  float* bn_scale = (float*)alloc(64 * 4);
  float* bn_shift = (float*)alloc(64 * 4);
  if (off > ws_size) return;  // workspace too small -> fail loudly (zero output)

  int nscan = (N + 1023) / 1024;

  k_init<<<(N + 255) / 256, 256, 0, stream>>>(deg, bn_sum, bn_ssq, N);
  k_deg<<<(E + 255) / 256, 256, 0, stream>>>(dst, deg, E);
  k_scan_a<<<nscan, 1024, 0, stream>>>(deg, offs, bsum, N);
  k_scan_b<<<1, 1024, 0, stream>>>(bsum, nscan);
  k_scan_c<<<nscan, 1024, 0, stream>>>(offs, bsum, cursor, N);
  k_scatter<<<(E + 255) / 256, 256, 0, stream>>>(dst, cursor, csr, E);

  k_edge_agg<<<(N + 3) / 4, 256, 0, stream>>>(node_feat, edge_feat, pre_W, pre_b,
                                              src, offs, deg, csr, agg, aux, N);

  k_post1<<<(N + 15) / 16, 256, 0, stream>>>(node_feat, agg, aux, post_W1,
                                             post_b1, x1, bn_sum, bn_ssq, N);

  k_bnstat<<<1, 64, 0, stream>>>(bn_sum, bn_ssq, bn_gamma, bn_beta, bn_scale,
                                 bn_shift, 1.0f / (float)N);

  k_post2<<<(N + 3) / 4, 256, 0, stream>>>(x1, post_W2, post_b2, bn_scale,
                                           bn_shift, node_feat, out, N);
}

// Round 2
// 1115.057 us; speedup vs baseline: 1.5263x; 1.5263x over previous
//
#include <hip/hip_runtime.h>
#include <math.h>

#define EPSF 1e-5f

typedef __attribute__((ext_vector_type(8))) short bf16x8;
typedef __attribute__((ext_vector_type(4))) float f32x4;
typedef __attribute__((ext_vector_type(4))) unsigned short us4;
typedef __attribute__((ext_vector_type(8))) unsigned short us8;

static __device__ __forceinline__ unsigned short f2bf(float f) {
  unsigned u = __float_as_uint(f);
  u += 0x7fffu + ((u >> 16) & 1u);
  return (unsigned short)(u >> 16);
}
static __device__ __forceinline__ float bf2f(unsigned short h) {
  return __uint_as_float((unsigned)h << 16);
}
static __device__ __forceinline__ float bcastlane(float v, int l) {
  return __int_as_float(__builtin_amdgcn_readlane(__float_as_int(v), l));
}

// ---------------- init / histogram / scan / scatter (CSR build) -------------

__global__ __launch_bounds__(256) void k_init(int* __restrict__ deg,
                                              float* __restrict__ asum,
                                              float* __restrict__ assq,
                                              unsigned* __restrict__ amax,
                                              unsigned* __restrict__ amin,
                                              float* __restrict__ bn_sum,
                                              float* __restrict__ bn_ssq, int N) {
  long i = (long)blockIdx.x * 256 + threadIdx.x;
  long T = (long)N * 64;
  if (i < T) {
    asum[i] = 0.f;
    assq[i] = 0.f;
    amax[i] = 0u;             // e >= 0 after relu, so 0 is a valid max identity
    amin[i] = 0x7f800000u;    // +inf bits
  }
  if (i < N) deg[i] = 0;
  if (i < 64) { bn_sum[i] = 0.f; bn_ssq[i] = 0.f; }
}

__global__ __launch_bounds__(256) void k_deg(const int* __restrict__ dst,
                                             int* __restrict__ deg, int E) {
  int i = blockIdx.x * 256 + threadIdx.x;
  if (i < E) atomicAdd(&deg[dst[i]], 1);
}

__global__ __launch_bounds__(1024) void k_scan_a(const int* __restrict__ deg,
                                                 int* __restrict__ offs,
                                                 int* __restrict__ bsum, int N) {
  __shared__ int s[1024];
  int t = threadIdx.x;
  int i = blockIdx.x * 1024 + t;
  int v = (i < N) ? deg[i] : 0;
  s[t] = v;
  __syncthreads();
  for (int off = 1; off < 1024; off <<= 1) {
    int x = (t >= off) ? s[t - off] : 0;
    __syncthreads();
    s[t] += x;
    __syncthreads();
  }
  if (i < N) offs[i] = s[t] - v;
  if (t == 1023) bsum[blockIdx.x] = s[1023];
}

__global__ __launch_bounds__(1024) void k_scan_b(int* __restrict__ bsum, int nb) {
  __shared__ int s[1024];
  int t = threadIdx.x;
  int v = (t < nb) ? bsum[t] : 0;
  s[t] = v;
  __syncthreads();
  for (int off = 1; off < 1024; off <<= 1) {
    int x = (t >= off) ? s[t - off] : 0;
    __syncthreads();
    s[t] += x;
    __syncthreads();
  }
  if (t < nb) bsum[t] = s[t] - v;
}

__global__ __launch_bounds__(1024) void k_scan_c(int* __restrict__ offs,
                                                 const int* __restrict__ bsum,
                                                 int* __restrict__ cursor, int N) {
  int i = blockIdx.x * 1024 + threadIdx.x;
  if (i < N) {
    int o = offs[i] + bsum[blockIdx.x];
    offs[i] = o;
    cursor[i] = o;
  }
}

__global__ __launch_bounds__(256) void k_scatter(const int* __restrict__ dst,
                                                 int* __restrict__ cursor,
                                                 int* __restrict__ csr, int E) {
  int i = blockIdx.x * 256 + threadIdx.x;
  if (i < E) {
    int d = dst[i];
    int pos = atomicAdd(&cursor[d], 1);
    csr[pos] = i;
  }
}

// ---------------- degree scalers ---------------------------------------------

__global__ __launch_bounds__(256) void k_aux(const int* __restrict__ deg,
                                             float* __restrict__ aux4, int N) {
  int n = blockIdx.x * 256 + threadIdx.x;
  if (n >= N) return;
  int d = deg[n];
  float logD = logf((float)d + 1.f);
  f32x4 o;
  o.x = logD;                                    // amp scaler (AVG_LOG = 1)
  o.y = (d > 0) ? 1.f / fmaxf(logD, EPSF) : 0.f; // att scaler
  o.z = (d > 0) ? 1.f / (float)d : 0.f;          // 1/deg
  o.w = 0.f;
  *(f32x4*)(aux4 + (long)n * 4) = o;
}

// ---------------- weight prep: transpose + bf16 + K-pad ----------------------
// wtp: [64][168] bf16 of pre_W^T (K=144 padded to 168 incl. LDS-friendly pad)
// wt1: [64][840] bf16 of post_W1^T (K=832 padded to 840)

__global__ __launch_bounds__(256) void k_prep(const float* __restrict__ pre_W,
                                              const float* __restrict__ post_W1,
                                              unsigned short* __restrict__ wtp,
                                              unsigned short* __restrict__ wt1) {
  int idx = blockIdx.x * 256 + threadIdx.x;
  if (idx < 64 * 168) {
    int c = idx / 168, k = idx - c * 168;
    wtp[idx] = f2bf((k < 144) ? pre_W[k * 64 + c] : 0.f);
  }
  int j = idx - 64 * 168;
  if (j >= 0 && j < 64 * 840) {
    int c = j / 840, k = j - c * 840;
    wt1[j] = f2bf((k < 832) ? post_W1[k * 64 + c] : 0.f);
  }
}

// ---------------- phase 1: MFMA edge-MLP + fused segment aggregation ---------
// 64 CSR positions per block (4 waves x 16 rows). z = [h_src|h_dst|e_feat] in
// LDS bf16, W^T in LDS bf16; 16x16x32 MFMA; epilogue does relu+bias then
// run-length-batched atomics into per-node sum/ssq/max/min.

__global__ __launch_bounds__(256) void kA_edge(
    const float* __restrict__ nf, const float* __restrict__ efeat,
    const unsigned short* __restrict__ wtp, const float* __restrict__ pre_b,
    const int* __restrict__ src, const int* __restrict__ dst,
    const int* __restrict__ csr, float* __restrict__ asum,
    float* __restrict__ assq, unsigned* __restrict__ amax,
    unsigned* __restrict__ amin, int E) {
  __shared__ unsigned short zt[64][168];
  __shared__ unsigned short wt[64][168];
  __shared__ unsigned short ot[64][68];
  __shared__ int snS[64], dnS[64], eidS[64];
  int tid = threadIdx.x;
  int p0 = blockIdx.x * 64;

  if (tid < 64) {
    int p = p0 + tid;
    int e = (p < E) ? csr[p] : 0;
    eidS[tid] = e;
    snS[tid] = src[e];
    dnS[tid] = dst[e];
  }
  for (int idx = tid; idx < 1344; idx += 256)
    ((us8*)&wt[0][0])[idx] = ((const us8*)wtp)[idx];
  __syncthreads();

  // gather z rows: 42 us4-segments per row (144 real + pad to 168)
  for (int idx = tid; idx < 64 * 42; idx += 256) {
    int row = idx / 42, s = idx - row * 42;
    f32x4 v = {0.f, 0.f, 0.f, 0.f};
    if (s < 16)      v = *(const f32x4*)(nf + (long)snS[row] * 64 + s * 4);
    else if (s < 32) v = *(const f32x4*)(nf + (long)dnS[row] * 64 + (s - 16) * 4);
    else if (s < 36) v = *(const f32x4*)(efeat + (long)eidS[row] * 16 + (s - 32) * 4);
    us4 o;
    o.x = f2bf(v.x); o.y = f2bf(v.y); o.z = f2bf(v.z); o.w = f2bf(v.w);
    *(us4*)&zt[row][s * 4] = o;
  }
  __syncthreads();

  int lane = tid & 63, w = tid >> 6;
  int r0 = w * 16;
  const unsigned short* za = &zt[r0 + (lane & 15)][(lane >> 4) * 8];
  const unsigned short* wb = &wt[lane & 15][(lane >> 4) * 8];
  f32x4 acc[4] = {{0.f,0.f,0.f,0.f},{0.f,0.f,0.f,0.f},{0.f,0.f,0.f,0.f},{0.f,0.f,0.f,0.f}};
#pragma unroll
  for (int kk = 0; kk < 5; kk++) {
    bf16x8 a = *(const bf16x8*)(za + kk * 32);
#pragma unroll
    for (int c = 0; c < 4; c++) {
      bf16x8 b = *(const bf16x8*)(wb + c * (16 * 168) + kk * 32);
      acc[c] = __builtin_amdgcn_mfma_f32_16x16x32_bf16(a, b, acc[c], 0, 0, 0);
    }
  }

  // epilogue: bias + relu -> ot (each wave writes only its own 16 rows)
  int rb = r0 + (lane >> 4) * 4;
#pragma unroll
  for (int c = 0; c < 4; c++) {
    int col = c * 16 + (lane & 15);
    float bv = pre_b[col];
#pragma unroll
    for (int r = 0; r < 4; r++)
      ot[rb + r][col] = f2bf(fmaxf(acc[c][r] + bv, 0.f));
  }

  // fused aggregation: lane = channel; sweep own wave's 16 rows, flush per run
  float s = 0.f, q = 0.f, mx = 0.f, mn = 3.4e38f;
  int cur = -1;
  for (int i = 0; i < 16; i++) {
    int row = r0 + i;
    if (p0 + row >= E) break;
    int nd = dnS[row];
    if (nd != cur) {
      if (cur >= 0) {
        long b = (long)cur * 64 + lane;
        atomicAdd(&asum[b], s);
        atomicAdd(&assq[b], q);
        atomicMax(&amax[b], __float_as_uint(mx));
        atomicMin(&amin[b], __float_as_uint(mn));
      }
      cur = nd; s = 0.f; q = 0.f; mx = 0.f; mn = 3.4e38f;
    }
    float v = bf2f(ot[row][lane]);
    s += v;
    q = fmaf(v, v, q);
    mx = fmaxf(mx, v);
    mn = fminf(mn, v);
  }
  if (cur >= 0) {
    long b = (long)cur * 64 + lane;
    atomicAdd(&asum[b], s);
    atomicAdd(&assq[b], q);
    atomicMax(&amax[b], __float_as_uint(mx));
    atomicMin(&amin[b], __float_as_uint(mn));
  }
}

// ---------------- phase 2: MFMA post1 GEMM + BN partials ---------------------
// 32 nodes per block (4 waves: 2 row-halves x 2 col-halves). h[832] built on
// the fly from node_feat + finalized aggregates x scalers, bf16 in LDS.

__global__ __launch_bounds__(256) void kC_post1(
    const float* __restrict__ nf, const float* __restrict__ asum,
    const float* __restrict__ assq, const float* __restrict__ amaxf,
    const float* __restrict__ aminf, const float* __restrict__ aux4,
    const unsigned short* __restrict__ wt1, const float* __restrict__ b1,
    unsigned short* __restrict__ x1, float* __restrict__ bn_sum,
    float* __restrict__ bn_ssq, int N) {
  __shared__ unsigned short ht[32][840];
  int tid = threadIdx.x;
  int n0 = blockIdx.x * 32;

  for (int idx = tid; idx < 32 * 210; idx += 256) {
    int row = idx / 210, s4 = idx - row * 210;
    int n = n0 + row;
    us4 o = {0, 0, 0, 0};
    if (n < N) {
      int c0 = s4 * 4;
      if (c0 < 64) {
        f32x4 v = *(const f32x4*)(nf + (long)n * 64 + c0);
        o.x = f2bf(v.x); o.y = f2bf(v.y); o.z = f2bf(v.z); o.w = f2bf(v.w);
      } else if (c0 < 832) {
        int qd = c0 - 64;
        int grp = qd >> 8, qq = qd & 255;
        int stat = qq >> 6, col = qq & 63;
        f32x4 ax = *(const f32x4*)(aux4 + (long)n * 4);
        float invd = ax.z;
        float sc = (grp == 0) ? 1.f : ((grp == 1) ? ax.x : ax.y);
        f32x4 v = {0.f, 0.f, 0.f, 0.f};
        long b = (long)n * 64 + col;
        if (stat == 0) {
          f32x4 t = *(const f32x4*)(asum + b);
          v.x = t.x * invd; v.y = t.y * invd; v.z = t.z * invd; v.w = t.w * invd;
        } else if (stat == 1) {
          v = *(const f32x4*)(amaxf + b);  // deg==0 slots already 0
        } else if (stat == 2) {
          if (invd > 0.f) v = *(const f32x4*)(aminf + b);
        } else {
          if (invd > 0.f) {
            f32x4 t = *(const f32x4*)(asum + b);
            f32x4 u = *(const f32x4*)(assq + b);
            float m;
            m = t.x * invd; v.x = sqrtf(fmaxf(u.x * invd - m * m, 0.f) + EPSF);
            m = t.y * invd; v.y = sqrtf(fmaxf(u.y * invd - m * m, 0.f) + EPSF);
            m = t.z * invd; v.z = sqrtf(fmaxf(u.z * invd - m * m, 0.f) + EPSF);
            m = t.w * invd; v.w = sqrtf(fmaxf(u.w * invd - m * m, 0.f) + EPSF);
          }
        }
        o.x = f2bf(v.x * sc); o.y = f2bf(v.y * sc);
        o.z = f2bf(v.z * sc); o.w = f2bf(v.w * sc);
      }
    }
    *(us4*)&ht[row][s4 * 4] = o;
  }
  __syncthreads();

  int lane = tid & 63, w = tid >> 6;
  int r0 = (w & 1) * 16, c0 = (w >> 1) * 32;
  const unsigned short* ap = &ht[r0 + (lane & 15)][(lane >> 4) * 8];
  const unsigned short* bp =
      wt1 + (long)(c0 + (lane & 15)) * 840 + (lane >> 4) * 8;
  f32x4 acc0 = {0.f, 0.f, 0.f, 0.f}, acc1 = {0.f, 0.f, 0.f, 0.f};
#pragma unroll 2
  for (int kk = 0; kk < 26; kk++) {
    bf16x8 a = *(const bf16x8*)(ap + kk * 32);
    bf16x8 b0 = *(const bf16x8*)(bp + kk * 32);
    bf16x8 b1f = *(const bf16x8*)(bp + 16 * 840 + kk * 32);
    acc0 = __builtin_amdgcn_mfma_f32_16x16x32_bf16(a, b0, acc0, 0, 0, 0);
    acc1 = __builtin_amdgcn_mfma_f32_16x16x32_bf16(a, b1f, acc1, 0, 0, 0);
  }
  __syncthreads();  // all waves done reading ht; reuse as fp32 [32][68]

  float* sx = (float*)&ht[0][0];
  int rb = r0 + (lane >> 4) * 4;
#pragma unroll
  for (int f = 0; f < 2; f++) {
    int col = c0 + f * 16 + (lane & 15);
    float bv = b1[col];
    f32x4 av = f ? acc1 : acc0;
#pragma unroll
    for (int r = 0; r < 4; r++) {
      int n = n0 + rb + r;
      float x = (n < N) ? fmaxf(av[r] + bv, 0.f) : 0.f;
      sx[(rb + r) * 68 + col] = x;
    }
  }
  __syncthreads();

  for (int idx = tid; idx < 32 * 16; idx += 256) {
    int row = idx >> 4, s4 = idx & 15;
    int n = n0 + row;
    if (n < N) {
      const float* p = sx + row * 68 + s4 * 4;
      us4 o;
      o.x = f2bf(p[0]); o.y = f2bf(p[1]); o.z = f2bf(p[2]); o.w = f2bf(p[3]);
      *(us4*)(x1 + (long)n * 64 + s4 * 4) = o;
    }
  }
  if (tid < 64) {
    float s = 0.f, s2 = 0.f;
    for (int r = 0; r < 32; r++) {
      float v = sx[r * 68 + tid];
      s += v;
      s2 = fmaf(v, v, s2);
    }
    atomicAdd(&bn_sum[tid], s);
    atomicAdd(&bn_ssq[tid], s2);
  }
}

// ---------------- BN stats finalize -----------------------------------------

__global__ __launch_bounds__(64) void k_bnstat(
    const float* __restrict__ bn_sum, const float* __restrict__ bn_ssq,
    const float* __restrict__ gamma, const float* __restrict__ beta,
    float* __restrict__ scale, float* __restrict__ shift, float invN) {
  int j = threadIdx.x;
  float mu = bn_sum[j] * invN;
  float v = fmaxf(bn_ssq[j] * invN - mu * mu, 0.f);
  float sc = gamma[j] / sqrtf(v + EPSF);
  scale[j] = sc;
  shift[j] = beta[j] - mu * sc;
}

// ---------------- out = relu(BN(x1) @ W2 + b2) + h_in ------------------------

__global__ __launch_bounds__(256) void k_post2(
    const unsigned short* __restrict__ x1, const float* __restrict__ post_W2,
    const float* __restrict__ post_b2, const float* __restrict__ scale,
    const float* __restrict__ shift, const float* __restrict__ nf,
    float* __restrict__ out, int N) {
  __shared__ float W2l[64 * 64];
  int tid = threadIdx.x;
  for (int idx = tid; idx < 4096; idx += 256) W2l[idx] = post_W2[idx];
  __syncthreads();
  int lane = tid & 63;
  int n = blockIdx.x * 4 + (tid >> 6);
  if (n >= N) return;
  float xv = bf2f(x1[(long)n * 64 + lane]) * scale[lane] + shift[lane];
  float acca = post_b2[lane], accb = 0.f;
#pragma unroll
  for (int k = 0; k < 64; k += 2) {
    acca = fmaf(bcastlane(xv, k), W2l[k * 64 + lane], acca);
    accb = fmaf(bcastlane(xv, k + 1), W2l[(k + 1) * 64 + lane], accb);
  }
  out[(long)n * 64 + lane] =
      fmaxf(acca + accb, 0.f) + nf[(long)n * 64 + lane];
}

// ----------------------------------------------------------------------------

extern "C" void kernel_launch(void* const* d_in, const int* in_sizes, int n_in,
                              void* d_out, int out_size, void* d_ws, size_t ws_size,
                              hipStream_t stream) {
  const float* node_feat = (const float*)d_in[0];
  const float* edge_feat = (const float*)d_in[1];
  const float* pre_W = (const float*)d_in[2];
  const float* pre_b = (const float*)d_in[3];
  const float* post_W1 = (const float*)d_in[4];
  const float* post_b1 = (const float*)d_in[5];
  const float* bn_gamma = (const float*)d_in[6];
  const float* bn_beta = (const float*)d_in[7];
  const float* post_W2 = (const float*)d_in[8];
  const float* post_b2 = (const float*)d_in[9];
  const int* src = (const int*)d_in[10];
  const int* dst = (const int*)d_in[11];
  float* out = (float*)d_out;

  int N = in_sizes[0] / 64;
  int E = in_sizes[10];

  char* ws = (char*)d_ws;
  size_t off = 0;
  auto alloc = [&](size_t bytes) -> void* {
    void* p = ws + off;
    off += (bytes + 255) & ~(size_t)255;
    return p;
  };
  int* deg = (int*)alloc((size_t)N * 4);
  int* offs = (int*)alloc((size_t)N * 4);
  int* cursor = (int*)alloc((size_t)N * 4);
  int* csr = (int*)alloc((size_t)E * 4);
  int* bsum = (int*)alloc(1024 * 4);
  float* asum = (float*)alloc((size_t)N * 64 * 4);
  float* assq = (float*)alloc((size_t)N * 64 * 4);
  unsigned* amax = (unsigned*)alloc((size_t)N * 64 * 4);
  unsigned* amin = (unsigned*)alloc((size_t)N * 64 * 4);
  float* aux4 = (float*)alloc((size_t)N * 4 * 4);
  unsigned short* x1 = (unsigned short*)alloc((size_t)N * 64 * 2);
  unsigned short* wtp = (unsigned short*)alloc(64 * 168 * 2);
  unsigned short* wt1 = (unsigned short*)alloc(64 * 840 * 2);
  float* bn_sum = (float*)alloc(64 * 4);
  float* bn_ssq = (float*)alloc(64 * 4);
  float* bn_scale = (float*)alloc(64 * 4);
  float* bn_shift = (float*)alloc(64 * 4);
  if (off > ws_size) return;  // fail loudly (output stays poisoned)

  int nscan = (N + 1023) / 1024;

  k_init<<<(N * 64 + 255) / 256, 256, 0, stream>>>(deg, asum, assq, amax, amin,
                                                   bn_sum, bn_ssq, N);
  k_deg<<<(E + 255) / 256, 256, 0, stream>>>(dst, deg, E);
  k_aux<<<(N + 255) / 256, 256, 0, stream>>>(deg, aux4, N);
  k_scan_a<<<nscan, 1024, 0, stream>>>(deg, offs, bsum, N);
  k_scan_b<<<1, 1024, 0, stream>>>(bsum, nscan);
  k_scan_c<<<nscan, 1024, 0, stream>>>(offs, bsum, cursor, N);
  k_scatter<<<(E + 255) / 256, 256, 0, stream>>>(dst, cursor, csr, E);
  k_prep<<<(64 * 168 + 64 * 840 + 255) / 256, 256, 0, stream>>>(pre_W, post_W1,
                                                                wtp, wt1);

  kA_edge<<<(E + 63) / 64, 256, 0, stream>>>(node_feat, edge_feat, wtp, pre_b,
                                             src, dst, csr, asum, assq, amax,
                                             amin, E);

  kC_post1<<<(N + 31) / 32, 256, 0, stream>>>(
      node_feat, asum, assq, (const float*)amax, (const float*)amin, aux4, wt1,
      post_b1, x1, bn_sum, bn_ssq, N);

  k_bnstat<<<1, 64, 0, stream>>>(bn_sum, bn_ssq, bn_gamma, bn_beta, bn_scale,
                                 bn_shift, 1.0f / (float)N);

  k_post2<<<(N + 3) / 4, 256, 0, stream>>>(x1, post_W2, post_b2, bn_scale,
                                           bn_shift, node_feat, out, N);
}

// Round 3
// 641.030 us; speedup vs baseline: 2.6551x; 1.7395x over previous
//
#include <hip/hip_runtime.h>
#include <math.h>

#define EPSF 1e-5f

typedef __attribute__((ext_vector_type(8))) short bf16x8;
typedef __attribute__((ext_vector_type(4))) float f32x4;
typedef __attribute__((ext_vector_type(4))) unsigned short us4;

static __device__ __forceinline__ unsigned short f2bf(float f) {
  unsigned u = __float_as_uint(f);
  u += 0x7fffu + ((u >> 16) & 1u);
  return (unsigned short)(u >> 16);
}
static __device__ __forceinline__ float bf2f(unsigned short h) {
  return __uint_as_float((unsigned)h << 16);
}
static __device__ __forceinline__ float bcastlane(float v, int l) {
  return __int_as_float(__builtin_amdgcn_readlane(__float_as_int(v), l));
}

// ---------------- init / histogram / scan / scatter (CSR build) -------------

__global__ __launch_bounds__(256) void k_init(int* __restrict__ deg,
                                              float* __restrict__ bn_sum,
                                              float* __restrict__ bn_ssq, int N) {
  int i = blockIdx.x * 256 + threadIdx.x;
  if (i < N) deg[i] = 0;
  if (i < 64) { bn_sum[i] = 0.f; bn_ssq[i] = 0.f; }
}

__global__ __launch_bounds__(256) void k_deg(const int* __restrict__ dst,
                                             int* __restrict__ deg, int E) {
  int i = blockIdx.x * 256 + threadIdx.x;
  if (i < E) atomicAdd(&deg[dst[i]], 1);
}

__global__ __launch_bounds__(256) void k_aux(const int* __restrict__ deg,
                                             float* __restrict__ aux2, int N) {
  int n = blockIdx.x * 256 + threadIdx.x;
  if (n >= N) return;
  int d = deg[n];
  float logD = logf((float)d + 1.f);
  aux2[n * 2] = logD;                                      // amp scaler
  aux2[n * 2 + 1] = (d > 0) ? 1.f / fmaxf(logD, EPSF) : 0.f;  // att scaler
}

__global__ __launch_bounds__(1024) void k_scan_a(const int* __restrict__ deg,
                                                 int* __restrict__ offs,
                                                 int* __restrict__ bsum, int N) {
  __shared__ int s[1024];
  int t = threadIdx.x;
  int i = blockIdx.x * 1024 + t;
  int v = (i < N) ? deg[i] : 0;
  s[t] = v;
  __syncthreads();
  for (int off = 1; off < 1024; off <<= 1) {
    int x = (t >= off) ? s[t - off] : 0;
    __syncthreads();
    s[t] += x;
    __syncthreads();
  }
  if (i < N) offs[i] = s[t] - v;
  if (t == 1023) bsum[blockIdx.x] = s[1023];
}

__global__ __launch_bounds__(1024) void k_scan_b(int* __restrict__ bsum, int nb) {
  __shared__ int s[1024];
  int t = threadIdx.x;
  int v = (t < nb) ? bsum[t] : 0;
  s[t] = v;
  __syncthreads();
  for (int off = 1; off < 1024; off <<= 1) {
    int x = (t >= off) ? s[t - off] : 0;
    __syncthreads();
    s[t] += x;
    __syncthreads();
  }
  if (t < nb) bsum[t] = s[t] - v;
}

__global__ __launch_bounds__(1024) void k_scan_c(int* __restrict__ offs,
                                                 const int* __restrict__ bsum,
                                                 int* __restrict__ cursor, int N) {
  int i = blockIdx.x * 1024 + threadIdx.x;
  if (i < N) {
    int o = offs[i] + bsum[blockIdx.x];
    offs[i] = o;
    cursor[i] = o;
  }
}

__global__ __launch_bounds__(256) void k_scatter(const int* __restrict__ dst,
                                                 const int* __restrict__ src,
                                                 int* __restrict__ cursor,
                                                 int* __restrict__ csr,
                                                 int* __restrict__ srcs, int E) {
  int i = blockIdx.x * 256 + threadIdx.x;
  if (i < E) {
    int d = dst[i];
    int pos = atomicAdd(&cursor[d], 1);
    csr[pos] = i;
    srcs[pos] = src[i];
  }
}

// ---------------- weight prep -------------------------------------------------
// wsdt: [128][64] bf16, row c<64 -> Ws^T col c, row c>=64 -> Wd^T col c-64
// wt1 : [64][840] bf16 of post_W1^T (K=832 padded to 840)

__global__ __launch_bounds__(256) void k_prep(const float* __restrict__ pre_W,
                                              const float* __restrict__ post_W1,
                                              unsigned short* __restrict__ wsdt,
                                              unsigned short* __restrict__ wt1) {
  int idx = blockIdx.x * 256 + threadIdx.x;
  if (idx < 128 * 64) {
    int c = idx >> 6, k = idx & 63;
    float v = (c < 64) ? pre_W[k * 64 + c] : pre_W[(64 + k) * 64 + (c - 64)];
    wsdt[idx] = f2bf(v);
  }
  int j = idx - 128 * 64;
  if (j >= 0 && j < 64 * 840) {
    int c = j / 840, k = j - c * 840;
    wt1[j] = f2bf((k < 832) ? post_W1[k * 64 + c] : 0.f);
  }
}

// ---------------- node projections: P_s = nf@Ws, P_d = nf@Wd + b (MFMA) ------

__global__ __launch_bounds__(256) void kB_proj(
    const float* __restrict__ nf, const unsigned short* __restrict__ wsdt,
    const float* __restrict__ pre_b, unsigned short* __restrict__ ps,
    unsigned short* __restrict__ pd, int N) {
  __shared__ unsigned short at[64][72];
  int tid = threadIdx.x;
  int n0 = blockIdx.x * 64;
  for (int idx = tid; idx < 64 * 16; idx += 256) {
    int row = idx >> 4, s4 = idx & 15;
    int n = n0 + row;
    us4 o = {0, 0, 0, 0};
    if (n < N) {
      f32x4 v = *(const f32x4*)(nf + (long)n * 64 + s4 * 4);
      o.x = f2bf(v.x); o.y = f2bf(v.y); o.z = f2bf(v.z); o.w = f2bf(v.w);
    }
    *(us4*)&at[row][s4 * 4] = o;
    if (s4 < 2) { us4 z = {0, 0, 0, 0}; *(us4*)&at[row][64 + s4 * 4] = z; }
  }
  __syncthreads();
  int lane = tid & 63, w = tid >> 6;
  int r0 = w * 16;
  const unsigned short* ap = &at[r0 + (lane & 15)][(lane >> 4) * 8];
  const unsigned short* bp = wsdt + (lane & 15) * 64 + (lane >> 4) * 8;
  f32x4 acc[8];
#pragma unroll
  for (int c = 0; c < 8; c++) acc[c] = (f32x4){0.f, 0.f, 0.f, 0.f};
#pragma unroll
  for (int c = 0; c < 8; c++) {
#pragma unroll
    for (int kk = 0; kk < 2; kk++) {
      bf16x8 a = *(const bf16x8*)(ap + kk * 32);
      bf16x8 b = *(const bf16x8*)(bp + c * 1024 + kk * 32);
      acc[c] = __builtin_amdgcn_mfma_f32_16x16x32_bf16(a, b, acc[c], 0, 0, 0);
    }
  }
  int rb = r0 + (lane >> 4) * 4;
#pragma unroll
  for (int c = 0; c < 8; c++) {
    int col = c * 16 + (lane & 15);  // 0..127
    int cc = col & 63;
    float bv = (col >= 64) ? pre_b[cc] : 0.f;
#pragma unroll
    for (int r = 0; r < 4; r++) {
      int n = n0 + rb + r;
      if (n < N) {
        unsigned short val = f2bf(acc[c][r] + bv);
        if (col >= 64) pd[(long)n * 64 + cc] = val;
        else ps[(long)n * 64 + cc] = val;
      }
    }
  }
}

// ---------------- phase 1: streaming edge eval + per-node aggregation --------
// 1 wave per 16 nodes, lane = channel. e = relu(P_s[src] + P_d[dst] + ef@We).
// No LDS, no syncthreads, no atomics; stats finalized in registers.

__global__ __launch_bounds__(256) void kA_agg(
    const unsigned short* __restrict__ ps, const unsigned short* __restrict__ pd,
    const float* __restrict__ efeat, const float* __restrict__ pre_W,
    const int* __restrict__ srcs, const int* __restrict__ csr,
    const int* __restrict__ offs, const int* __restrict__ deg,
    unsigned short* __restrict__ aggb, int N) {
  int lane = threadIdx.x & 63;
  int wv = threadIdx.x >> 6;
  int nbase = (blockIdx.x * 4 + wv) * 16;
  float We[16];
#pragma unroll
  for (int k = 0; k < 16; k++) We[k] = pre_W[(128 + k) * 64 + lane];

  for (int ni = 0; ni < 16; ni++) {
    int n = nbase + ni;
    if (n >= N) return;
    int dc = deg[n];
    long ab = (long)n * 256 + lane;
    if (dc == 0) {
      aggb[ab] = 0; aggb[ab + 64] = 0; aggb[ab + 128] = 0; aggb[ab + 192] = 0;
      continue;
    }
    float pdv = bf2f(pd[(long)n * 64 + lane]);
    int p = offs[n], pe = p + dc;
    float s = 0.f, q = 0.f, mx = 0.f, mn = 3.4e38f;
    for (; p + 2 <= pe; p += 2) {
      int s0 = srcs[p], s1 = srcs[p + 1];
      int e0 = csr[p], e1 = csr[p + 1];
      float ps0 = bf2f(ps[(long)s0 * 64 + lane]);
      float ps1 = bf2f(ps[(long)s1 * 64 + lane]);
      float ef0 = (lane < 16) ? efeat[(long)e0 * 16 + lane] : 0.f;
      float ef1 = (lane < 16) ? efeat[(long)e1 * 16 + lane] : 0.f;
      float a0 = pdv, b0 = 0.f, a1 = pdv, b1 = 0.f;
#pragma unroll
      for (int k = 0; k < 16; k += 2) {
        a0 = fmaf(bcastlane(ef0, k), We[k], a0);
        b0 = fmaf(bcastlane(ef0, k + 1), We[k + 1], b0);
        a1 = fmaf(bcastlane(ef1, k), We[k], a1);
        b1 = fmaf(bcastlane(ef1, k + 1), We[k + 1], b1);
      }
      float v0 = fmaxf(ps0 + a0 + b0, 0.f);
      float v1 = fmaxf(ps1 + a1 + b1, 0.f);
      s += v0 + v1;
      q = fmaf(v0, v0, q);
      q = fmaf(v1, v1, q);
      mx = fmaxf(mx, fmaxf(v0, v1));
      mn = fminf(mn, fminf(v0, v1));
    }
    if (p < pe) {
      int s0 = srcs[p];
      int e0 = csr[p];
      float ps0 = bf2f(ps[(long)s0 * 64 + lane]);
      float ef0 = (lane < 16) ? efeat[(long)e0 * 16 + lane] : 0.f;
      float a0 = pdv, b0 = 0.f;
#pragma unroll
      for (int k = 0; k < 16; k += 2) {
        a0 = fmaf(bcastlane(ef0, k), We[k], a0);
        b0 = fmaf(bcastlane(ef0, k + 1), We[k + 1], b0);
      }
      float v0 = fmaxf(ps0 + a0 + b0, 0.f);
      s += v0;
      q = fmaf(v0, v0, q);
      mx = fmaxf(mx, v0);
      mn = fminf(mn, v0);
    }
    float invd = 1.f / (float)dc;
    float mean = s * invd;
    float var = fmaxf(q * invd - mean * mean, 0.f);
    float stdv = sqrtf(var + EPSF);
    aggb[ab] = f2bf(mean);
    aggb[ab + 64] = f2bf(mx);
    aggb[ab + 128] = f2bf(mn);
    aggb[ab + 192] = f2bf(stdv);
  }
}

// ---------------- phase 2: MFMA post1 GEMM + BN partials ---------------------

__global__ __launch_bounds__(256) void kC_post1(
    const float* __restrict__ nf, const unsigned short* __restrict__ aggb,
    const float* __restrict__ aux2, const unsigned short* __restrict__ wt1,
    const float* __restrict__ b1, unsigned short* __restrict__ x1,
    float* __restrict__ bn_sum, float* __restrict__ bn_ssq, int N) {
  __shared__ unsigned short ht[32][840];
  int tid = threadIdx.x;
  int n0 = blockIdx.x * 32;

  for (int idx = tid; idx < 32 * 210; idx += 256) {
    int row = idx / 210, s4 = idx - row * 210;
    int n = n0 + row;
    us4 o = {0, 0, 0, 0};
    if (n < N) {
      int c0 = s4 * 4;
      if (c0 < 64) {
        f32x4 v = *(const f32x4*)(nf + (long)n * 64 + c0);
        o.x = f2bf(v.x); o.y = f2bf(v.y); o.z = f2bf(v.z); o.w = f2bf(v.w);
      } else if (c0 < 832) {
        int qd = c0 - 64;
        int grp = qd >> 8, qq = qd & 255;
        us4 t = *(const us4*)(aggb + (long)n * 256 + qq);
        if (grp == 0) {
          o = t;
        } else {
          float sc = (grp == 1) ? aux2[n * 2] : aux2[n * 2 + 1];
          o.x = f2bf(bf2f(t.x) * sc);
          o.y = f2bf(bf2f(t.y) * sc);
          o.z = f2bf(bf2f(t.z) * sc);
          o.w = f2bf(bf2f(t.w) * sc);
        }
      }
    }
    *(us4*)&ht[row][s4 * 4] = o;
  }
  __syncthreads();

  int lane = tid & 63, w = tid >> 6;
  int r0 = (w & 1) * 16, c0 = (w >> 1) * 32;
  const unsigned short* ap = &ht[r0 + (lane & 15)][(lane >> 4) * 8];
  const unsigned short* bp =
      wt1 + (long)(c0 + (lane & 15)) * 840 + (lane >> 4) * 8;
  f32x4 acc0 = {0.f, 0.f, 0.f, 0.f}, acc1 = {0.f, 0.f, 0.f, 0.f};
#pragma unroll 2
  for (int kk = 0; kk < 26; kk++) {
    bf16x8 a = *(const bf16x8*)(ap + kk * 32);
    bf16x8 b0 = *(const bf16x8*)(bp + kk * 32);
    bf16x8 b1f = *(const bf16x8*)(bp + 16 * 840 + kk * 32);
    acc0 = __builtin_amdgcn_mfma_f32_16x16x32_bf16(a, b0, acc0, 0, 0, 0);
    acc1 = __builtin_amdgcn_mfma_f32_16x16x32_bf16(a, b1f, acc1, 0, 0, 0);
  }
  __syncthreads();  // all waves done reading ht; reuse as fp32 [32][68]

  float* sx = (float*)&ht[0][0];
  int rb = r0 + (lane >> 4) * 4;
#pragma unroll
  for (int f = 0; f < 2; f++) {
    int col = c0 + f * 16 + (lane & 15);
    float bv = b1[col];
    f32x4 av = f ? acc1 : acc0;
#pragma unroll
    for (int r = 0; r < 4; r++) {
      int n = n0 + rb + r;
      float x = (n < N) ? fmaxf(av[r] + bv, 0.f) : 0.f;
      sx[(rb + r) * 68 + col] = x;
    }
  }
  __syncthreads();

  for (int idx = tid; idx < 32 * 16; idx += 256) {
    int row = idx >> 4, s4 = idx & 15;
    int n = n0 + row;
    if (n < N) {
      const float* p = sx + row * 68 + s4 * 4;
      us4 o;
      o.x = f2bf(p[0]); o.y = f2bf(p[1]); o.z = f2bf(p[2]); o.w = f2bf(p[3]);
      *(us4*)(x1 + (long)n * 64 + s4 * 4) = o;
    }
  }
  if (tid < 64) {
    float s = 0.f, s2 = 0.f;
    for (int r = 0; r < 32; r++) {
      float v = sx[r * 68 + tid];
      s += v;
      s2 = fmaf(v, v, s2);
    }
    atomicAdd(&bn_sum[tid], s);
    atomicAdd(&bn_ssq[tid], s2);
  }
}

// ---------------- BN stats finalize -----------------------------------------

__global__ __launch_bounds__(64) void k_bnstat(
    const float* __restrict__ bn_sum, const float* __restrict__ bn_ssq,
    const float* __restrict__ gamma, const float* __restrict__ beta,
    float* __restrict__ scale, float* __restrict__ shift, float invN) {
  int j = threadIdx.x;
  float mu = bn_sum[j] * invN;
  float v = fmaxf(bn_ssq[j] * invN - mu * mu, 0.f);
  float sc = gamma[j] / sqrtf(v + EPSF);
  scale[j] = sc;
  shift[j] = beta[j] - mu * sc;
}

// ---------------- out = relu(BN(x1) @ W2 + b2) + h_in ------------------------

__global__ __launch_bounds__(256) void k_post2(
    const unsigned short* __restrict__ x1, const float* __restrict__ post_W2,
    const float* __restrict__ post_b2, const float* __restrict__ scale,
    const float* __restrict__ shift, const float* __restrict__ nf,
    float* __restrict__ out, int N) {
  __shared__ float W2l[64 * 64];
  int tid = threadIdx.x;
  for (int idx = tid; idx < 4096; idx += 256) W2l[idx] = post_W2[idx];
  __syncthreads();
  int lane = tid & 63;
  int n = blockIdx.x * 4 + (tid >> 6);
  if (n >= N) return;
  float xv = bf2f(x1[(long)n * 64 + lane]) * scale[lane] + shift[lane];
  float acca = post_b2[lane], accb = 0.f;
#pragma unroll
  for (int k = 0; k < 64; k += 2) {
    acca = fmaf(bcastlane(xv, k), W2l[k * 64 + lane], acca);
    accb = fmaf(bcastlane(xv, k + 1), W2l[(k + 1) * 64 + lane], accb);
  }
  out[(long)n * 64 + lane] =
      fmaxf(acca + accb, 0.f) + nf[(long)n * 64 + lane];
}

// ----------------------------------------------------------------------------

extern "C" void kernel_launch(void* const* d_in, const int* in_sizes, int n_in,
                              void* d_out, int out_size, void* d_ws, size_t ws_size,
                              hipStream_t stream) {
  const float* node_feat = (const float*)d_in[0];
  const float* edge_feat = (const float*)d_in[1];
  const float* pre_W = (const float*)d_in[2];
  const float* pre_b = (const float*)d_in[3];
  const float* post_W1 = (const float*)d_in[4];
  const float* post_b1 = (const float*)d_in[5];
  const float* bn_gamma = (const float*)d_in[6];
  const float* bn_beta = (const float*)d_in[7];
  const float* post_W2 = (const float*)d_in[8];
  const float* post_b2 = (const float*)d_in[9];
  const int* src = (const int*)d_in[10];
  const int* dst = (const int*)d_in[11];
  float* out = (float*)d_out;

  int N = in_sizes[0] / 64;
  int E = in_sizes[10];

  char* ws = (char*)d_ws;
  size_t off = 0;
  auto alloc = [&](size_t bytes) -> void* {
    void* p = ws + off;
    off += (bytes + 255) & ~(size_t)255;
    return p;
  };
  int* deg = (int*)alloc((size_t)N * 4);
  int* offs = (int*)alloc((size_t)N * 4);
  int* cursor = (int*)alloc((size_t)N * 4);
  int* csr = (int*)alloc((size_t)E * 4);
  int* srcs = (int*)alloc((size_t)E * 4);
  int* bsum = (int*)alloc(1024 * 4);
  unsigned short* aggb = (unsigned short*)alloc((size_t)N * 256 * 2);
  float* aux2 = (float*)alloc((size_t)N * 2 * 4);
  unsigned short* psb = (unsigned short*)alloc((size_t)N * 64 * 2);
  unsigned short* pdb = (unsigned short*)alloc((size_t)N * 64 * 2);
  unsigned short* x1 = (unsigned short*)alloc((size_t)N * 64 * 2);
  unsigned short* wsdt = (unsigned short*)alloc(128 * 64 * 2);
  unsigned short* wt1 = (unsigned short*)alloc(64 * 840 * 2);
  float* bn_sum = (float*)alloc(64 * 4);
  float* bn_ssq = (float*)alloc(64 * 4);
  float* bn_scale = (float*)alloc(64 * 4);
  float* bn_shift = (float*)alloc(64 * 4);
  if (off > ws_size) return;  // fail loudly (output stays poisoned)

  int nscan = (N + 1023) / 1024;

  k_init<<<(N + 255) / 256, 256, 0, stream>>>(deg, bn_sum, bn_ssq, N);
  k_deg<<<(E + 255) / 256, 256, 0, stream>>>(dst, deg, E);
  k_aux<<<(N + 255) / 256, 256, 0, stream>>>(deg, aux2, N);
  k_scan_a<<<nscan, 1024, 0, stream>>>(deg, offs, bsum, N);
  k_scan_b<<<1, 1024, 0, stream>>>(bsum, nscan);
  k_scan_c<<<nscan, 1024, 0, stream>>>(offs, bsum, cursor, N);
  k_scatter<<<(E + 255) / 256, 256, 0, stream>>>(dst, src, cursor, csr, srcs, E);
  k_prep<<<(128 * 64 + 64 * 840 + 255) / 256, 256, 0, stream>>>(pre_W, post_W1,
                                                                wsdt, wt1);
  kB_proj<<<(N + 63) / 64, 256, 0, stream>>>(node_feat, wsdt, pre_b, psb, pdb, N);

  kA_agg<<<(N + 63) / 64, 256, 0, stream>>>(psb, pdb, edge_feat, pre_W, srcs,
                                            csr, offs, deg, aggb, N);

  kC_post1<<<(N + 31) / 32, 256, 0, stream>>>(node_feat, aggb, aux2, wt1,
                                              post_b1, x1, bn_sum, bn_ssq, N);

  k_bnstat<<<1, 64, 0, stream>>>(bn_sum, bn_ssq, bn_gamma, bn_beta, bn_scale,
                                 bn_shift, 1.0f / (float)N);

  k_post2<<<(N + 3) / 4, 256, 0, stream>>>(x1, post_W2, post_b2, bn_scale,
                                           bn_shift, node_feat, out, N);
}